// Round 1
// baseline (99.509 us; speedup 1.0000x reference)
//
#include <hip/hip_runtime.h>
#include <math.h>

// Problem constants (from reference): B=4, N=512, M=512, ZD=128, YD=2, XD=1
#define B_  4
#define N_  512
#define M_  512
#define ZD_ 128
#define YD_ 2
#define XD_ 1

// Tiling: each block has GROUPS c-groups of ZD_ threads; each group covers TM m-values.
#define GROUPS 2
#define TM     2
#define BLOCK  (GROUPS * ZD_)   // 256

__global__ __launch_bounds__(BLOCK)
void decoder_kernel(const float* __restrict__ t,
                    const float* __restrict__ z,
                    const float* __restrict__ x,
                    const float* __restrict__ sigma,
                    const float* __restrict__ W,
                    const float* __restrict__ bias,
                    float* __restrict__ out)
{
    __shared__ float ts[N_];                       // per-b t sums (XD summed)
    __shared__ float accs[GROUPS * TM * ZD_];      // per (group,mtile,c) accumulators

    const int b   = blockIdx.y;
    const int tid = threadIdx.x;
    const int mi  = tid / ZD_;        // c-group 0..GROUPS-1
    const int c   = tid % ZD_;        // channel (lane-contiguous -> coalesced z)
    const int m0  = (blockIdx.x * GROUPS + mi) * TM;

    // Stage t sums for this b into LDS (XD=1 so just a copy, but keep sum form).
    for (int n = tid; n < N_; n += BLOCK) {
        float s = 0.f;
        #pragma unroll
        for (int d = 0; d < XD_; ++d) s += t[((size_t)b * N_ + n) * XD_ + d];
        ts[n] = s;
    }
    __syncthreads();

    // x sums for this group's TM m-values.
    float xs[TM];
    #pragma unroll
    for (int j = 0; j < TM; ++j) {
        float s = 0.f;
        #pragma unroll
        for (int d = 0; d < XD_; ++d) s += x[((size_t)b * M_ + m0 + j) * XD_ + d];
        xs[j] = s;
    }

    // Per-channel RBF coefficient: exp(-0.5*(d/scale)^2) = exp(a * d^2)
    const float sc = __expf(sigma[c]);
    const float a  = -0.5f / (sc * sc);

    const float* zp = z + (size_t)b * N_ * ZD_ + c;

    float acc[TM];
    #pragma unroll
    for (int j = 0; j < TM; ++j) acc[j] = 0.f;

    // Main loop over grid points n: one z load, TM exp+fma.
    #pragma unroll 4
    for (int n = 0; n < N_; ++n) {
        const float zv = zp[(size_t)n * ZD_];
        const float tn = ts[n];
        #pragma unroll
        for (int j = 0; j < TM; ++j) {
            const float d = xs[j] - tn;
            const float e = __expf(a * d * d);   // v_exp_f32 path
            acc[j] = fmaf(zv, e, acc[j]);
        }
    }

    #pragma unroll
    for (int j = 0; j < TM; ++j)
        accs[(mi * TM + j) * ZD_ + c] = acc[j];
    __syncthreads();

    // Epilogue: out[b,m,y] = sum_c W[y,c]*acc[g,c] + bias[y]
    // GROUPS*TM m-values x YD outputs = 8 dots of length ZD.
    const int nout = GROUPS * TM * YD_;
    if (tid < nout) {
        const int y = tid % YD_;
        const int g = tid / YD_;                 // = mi*TM + j
        float s = bias[y];
        const float* wr = W + (size_t)y * ZD_;
        const float* ar = accs + (size_t)g * ZD_;
        for (int cc = 0; cc < ZD_; ++cc)
            s = fmaf(wr[cc], ar[cc], s);
        const int m = (blockIdx.x * GROUPS + g / TM) * TM + (g % TM);
        out[((size_t)b * M_ + m) * YD_ + y] = s;
    }
}

extern "C" void kernel_launch(void* const* d_in, const int* in_sizes, int n_in,
                              void* d_out, int out_size, void* d_ws, size_t ws_size,
                              hipStream_t stream) {
    const float* t     = (const float*)d_in[0];
    const float* z     = (const float*)d_in[1];
    const float* x     = (const float*)d_in[2];
    const float* sigma = (const float*)d_in[3];
    const float* W     = (const float*)d_in[4];
    const float* bias  = (const float*)d_in[5];
    float* out = (float*)d_out;

    dim3 grid(M_ / (GROUPS * TM), B_);   // (128, 4) = 512 blocks
    dim3 block(BLOCK);                   // 256 threads
    decoder_kernel<<<grid, block, 0, stream>>>(t, z, x, sigma, W, bias, out);
}

// Round 2
// 83.045 us; speedup vs baseline: 1.1982x; 1.1982x over previous
//
#include <hip/hip_runtime.h>
#include <math.h>

// Problem constants: B=4, N=512, M=512, ZD=128, YD=2, XD=1
#define B_  4
#define N_  512
#define M_  512
#define ZD_ 128
#define YD_ 2
#define XD_ 1

#define GROUPS 2          // c-groups per block (each ZD_ threads)
#define TM     2          // m-values per group
#define BLOCK  (GROUPS * ZD_)   // 256
#define NSPLIT 4          // n-dimension split (blocks accumulate via atomics)
#define NCHUNK (N_ / NSPLIT)    // 128

#define LOG2E_HALF 0.72134752044f   // 0.5*log2(e)

__global__ __launch_bounds__(BLOCK)
void decoder_kernel(const float* __restrict__ t,
                    const float* __restrict__ z,
                    const float* __restrict__ x,
                    const float* __restrict__ sigma,
                    const float* __restrict__ W,
                    const float* __restrict__ bias,
                    float* __restrict__ out)
{
    __shared__ float2 ts2[NCHUNK];               // {t_n, t_n^2} for this n-chunk
    __shared__ float  accs[GROUPS * TM * ZD_];   // scaled accumulators

    const int b   = blockIdx.y;
    const int nz  = blockIdx.z;                  // n-chunk index
    const int n0  = nz * NCHUNK;
    const int tid = threadIdx.x;
    const int mi  = tid >> 7;                    // c-group 0..1
    const int c   = tid & (ZD_ - 1);             // channel, lane-contiguous
    const int m0  = (blockIdx.x * GROUPS + mi) * TM;

    // Stage {t, t^2} for this chunk.
    if (tid < NCHUNK) {
        const float tv = t[(size_t)b * N_ + n0 + tid];   // XD=1
        ts2[tid] = make_float2(tv, tv * tv);
    }
    __syncthreads();

    // Per-channel exp2-domain coefficient: kernel = 2^(a2*d^2), a2 = -0.5*log2e/sc^2
    const float sc = __expf(sigma[c]);
    const float a2 = -LOG2E_HALF / (sc * sc);

    // Per-m precomputed: A_j = a2*x^2 (hoisted out as final scale), Bx_j = -2*a2*x
    float Bx[TM], E[TM];
    #pragma unroll
    for (int j = 0; j < TM; ++j) {
        const float xv = x[(size_t)b * M_ + m0 + j];     // XD=1
        Bx[j] = -2.0f * a2 * xv;
        E[j]  = __builtin_amdgcn_exp2f(a2 * xv * xv);
    }

    const float* zp = z + ((size_t)b * N_ + n0) * ZD_ + c;

    float acc[TM];
    #pragma unroll
    for (int j = 0; j < TM; ++j) acc[j] = 0.f;

    // Main loop: per n -> 1 global load, 1 LDS b64 broadcast, 1 mul,
    // then per j: fma + v_exp_f32 + fma.
    #pragma unroll 8
    for (int n = 0; n < NCHUNK; ++n) {
        const float  zv = zp[(size_t)n * ZD_];
        const float2 tt = ts2[n];
        const float  w  = a2 * tt.y;             // a2 * t^2
        #pragma unroll
        for (int j = 0; j < TM; ++j) {
            const float p = fmaf(Bx[j], tt.x, w);
            const float e = __builtin_amdgcn_exp2f(p);
            acc[j] = fmaf(zv, e, acc[j]);
        }
    }

    #pragma unroll
    for (int j = 0; j < TM; ++j)
        accs[(mi * TM + j) * ZD_ + c] = E[j] * acc[j];
    __syncthreads();

    // Epilogue: 128 threads; 32 lanes per m-value, 4 c each, both y outputs.
    if (tid < GROUPS * TM * 32) {
        const int g = tid >> 5;                  // which m (0..3)
        const int l = tid & 31;
        float s0 = 0.f, s1 = 0.f;
        #pragma unroll
        for (int k = 0; k < 4; ++k) {
            const int cc = l + 32 * k;
            const float av = accs[g * ZD_ + cc];
            s0 = fmaf(W[cc], av, s0);
            s1 = fmaf(W[ZD_ + cc], av, s1);
        }
        #pragma unroll
        for (int d = 16; d >= 1; d >>= 1) {      // stays within 32-lane group
            s0 += __shfl_xor(s0, d);
            s1 += __shfl_xor(s1, d);
        }
        if (l == 0) {
            const int m = (blockIdx.x * GROUPS + (g / TM)) * TM + (g % TM);
            const float b0 = (nz == 0) ? bias[0] : 0.f;
            const float b1 = (nz == 0) ? bias[1] : 0.f;
            atomicAdd(out + ((size_t)b * M_ + m) * YD_ + 0, s0 + b0);
            atomicAdd(out + ((size_t)b * M_ + m) * YD_ + 1, s1 + b1);
        }
    }
}

extern "C" void kernel_launch(void* const* d_in, const int* in_sizes, int n_in,
                              void* d_out, int out_size, void* d_ws, size_t ws_size,
                              hipStream_t stream) {
    const float* t     = (const float*)d_in[0];
    const float* z     = (const float*)d_in[1];
    const float* x     = (const float*)d_in[2];
    const float* sigma = (const float*)d_in[3];
    const float* W     = (const float*)d_in[4];
    const float* bias  = (const float*)d_in[5];
    float* out = (float*)d_out;

    hipMemsetAsync(out, 0, (size_t)out_size * sizeof(float), stream);

    dim3 grid(M_ / (GROUPS * TM), B_, NSPLIT);   // (128, 4, 4) = 2048 blocks
    dim3 block(BLOCK);                            // 256 threads
    decoder_kernel<<<grid, block, 0, stream>>>(t, z, x, sigma, W, bias, out);
}

// Round 3
// 80.227 us; speedup vs baseline: 1.2403x; 1.0351x over previous
//
#include <hip/hip_runtime.h>
#include <math.h>

// Problem constants: B=4, N=512, M=512, ZD=128, YD=2, XD=1
#define B_  4
#define N_  512
#define M_  512
#define ZD_ 128
#define YD_ 2
#define XD_ 1

#define TM      8                 // m-values per thread
#define NSUB    2                 // n-subgroups per block
#define BLOCK   (NSUB * ZD_)      // 256 threads
#define NSPLIT  8                 // grid-level n split
#define NBLOCKCHUNK (N_ / NSPLIT)         // 64 n per block
#define NCHUNK  (NBLOCKCHUNK / NSUB)      // 32 n per subgroup

#define LOG2E_HALF 0.72134752044f   // 0.5*log2(e)

__global__ __launch_bounds__(BLOCK)
void decoder_kernel(const float* __restrict__ t,
                    const float* __restrict__ z,
                    const float* __restrict__ x,
                    const float* __restrict__ sigma,
                    const float* __restrict__ W,
                    const float* __restrict__ bias,
                    float* __restrict__ out)
{
    __shared__ float2 ts2[NBLOCKCHUNK];          // {t_n, t_n^2} for block's n-chunk
    __shared__ float  accs[NSUB][TM][ZD_];       // per-subgroup scaled accumulators

    const int b   = blockIdx.y;
    const int nz  = blockIdx.z;
    const int n0  = nz * NBLOCKCHUNK;
    const int tid = threadIdx.x;
    const int sg  = tid >> 7;                    // n-subgroup 0..1
    const int c   = tid & (ZD_ - 1);             // channel, lane-contiguous
    const int m0  = blockIdx.x * TM;

    // Stage {t, t^2} for this block's 64 n-values.
    if (tid < NBLOCKCHUNK) {
        const float tv = t[(size_t)b * N_ + n0 + tid];   // XD=1
        ts2[tid] = make_float2(tv, tv * tv);
    }
    __syncthreads();

    // Per-channel exp2-domain coefficient: kernel = 2^(a2*d^2), a2 = -0.5*log2e/sc^2
    const float sc = __expf(sigma[c]);
    const float a2 = -LOG2E_HALF / (sc * sc);

    // Per-m: Bx_j = -2*a2*x_j ; E_j = 2^(a2*x_j^2) applied as final scale.
    float Bx[TM], E[TM];
    #pragma unroll
    for (int j = 0; j < TM; ++j) {
        const float xv = x[(size_t)b * M_ + m0 + j];     // XD=1
        Bx[j] = -2.0f * a2 * xv;
        E[j]  = __builtin_amdgcn_exp2f(a2 * xv * xv);
    }

    // This subgroup's n-range: [n0 + sg*NCHUNK, +NCHUNK)
    const float* zp = z + ((size_t)b * N_ + n0 + sg * NCHUNK) * ZD_ + c;

    float acc[TM];
    #pragma unroll
    for (int j = 0; j < TM; ++j) acc[j] = 0.f;

    // Main loop: per n -> 1 z load, 1 LDS b64 broadcast, 1 mul, then
    // 8 x (fma + v_exp_f32 + fma). 8 exps amortize each memory op.
    #pragma unroll 4
    for (int n = 0; n < NCHUNK; ++n) {
        const float  zv = zp[(size_t)n * ZD_];
        const float2 tt = ts2[sg * NCHUNK + n];
        const float  w  = a2 * tt.y;             // a2 * t^2
        #pragma unroll
        for (int j = 0; j < TM; ++j) {
            const float p = fmaf(Bx[j], tt.x, w);
            const float e = __builtin_amdgcn_exp2f(p);
            acc[j] = fmaf(zv, e, acc[j]);
        }
    }

    #pragma unroll
    for (int j = 0; j < TM; ++j)
        accs[sg][j][c] = E[j] * acc[j];
    __syncthreads();

    // Epilogue: 256 threads = 8 m x 32 lanes; each lane covers 4 c.
    {
        const int g = tid >> 5;                  // m index 0..7
        const int l = tid & 31;
        float s0 = 0.f, s1 = 0.f;
        #pragma unroll
        for (int k = 0; k < 4; ++k) {
            const int cc = l + 32 * k;
            const float av = accs[0][g][cc] + accs[1][g][cc];
            s0 = fmaf(W[cc], av, s0);
            s1 = fmaf(W[ZD_ + cc], av, s1);
        }
        #pragma unroll
        for (int d = 16; d >= 1; d >>= 1) {      // stays within 32-lane half
            s0 += __shfl_xor(s0, d);
            s1 += __shfl_xor(s1, d);
        }
        if (l == 0) {
            const float b0 = (nz == 0) ? bias[0] : 0.f;
            const float b1 = (nz == 0) ? bias[1] : 0.f;
            atomicAdd(out + ((size_t)b * M_ + m0 + g) * YD_ + 0, s0 + b0);
            atomicAdd(out + ((size_t)b * M_ + m0 + g) * YD_ + 1, s1 + b1);
        }
    }
}

extern "C" void kernel_launch(void* const* d_in, const int* in_sizes, int n_in,
                              void* d_out, int out_size, void* d_ws, size_t ws_size,
                              hipStream_t stream) {
    const float* t     = (const float*)d_in[0];
    const float* z     = (const float*)d_in[1];
    const float* x     = (const float*)d_in[2];
    const float* sigma = (const float*)d_in[3];
    const float* W     = (const float*)d_in[4];
    const float* bias  = (const float*)d_in[5];
    float* out = (float*)d_out;

    hipMemsetAsync(out, 0, (size_t)out_size * sizeof(float), stream);

    dim3 grid(M_ / TM, B_, NSPLIT);   // (64, 4, 8) = 2048 blocks
    dim3 block(BLOCK);                // 256 threads
    decoder_kernel<<<grid, block, 0, stream>>>(t, z, x, sigma, W, bias, out);
}